// Round 2
// baseline (236.301 us; speedup 1.0000x reference)
//
#include <hip/hip_runtime.h>

#define DIM           1024
#define BLK           64
#define NB            16      // DIM/BLK
#define RT            16      // rows per workgroup in main kernel
#define MAIN_THREADS  512
#define P68           68      // padded LDS row for expm (16B-aligned, bank-spread)

typedef float  f32x4  __attribute__((ext_vector_type(4)));
typedef short  bf16x8 __attribute__((ext_vector_type(8)));

// f32 -> bf16 bits, round-to-nearest-even (no NaN inputs here)
static __device__ __forceinline__ short f2bf(float f) {
    union { float f; unsigned u; } v; v.f = f;
    unsigned r = v.u + 0x7fffu + ((v.u >> 16) & 1u);
    return (short)(r >> 16);
}

// ---------------------------------------------------------------------------
// Kernel 0: normalize perm to int32 in ws. Detect int64 vs int32 at runtime:
// reading an int64 permutation buffer as int32 gives ~512 zero high-words;
// a genuine int32 permutation of [0,1024) has exactly one zero.
// ---------------------------------------------------------------------------
__global__ void decode_perm_kernel(const int* __restrict__ praw,
                                   int* __restrict__ pout) {
    __shared__ int zc;
    if (threadIdx.x == 0) zc = 0;
    __syncthreads();
    int local = 0;
    for (int i = threadIdx.x; i < DIM; i += blockDim.x)
        if (praw[i] == 0) local++;
    if (local) atomicAdd(&zc, local);
    __syncthreads();
    const bool is64 = (zc > 100);
    const long long* p64 = (const long long*)praw;
    for (int i = threadIdx.x; i < DIM; i += blockDim.x)
        pout[i] = is64 ? (int)p64[i] : praw[i];
}

// ---------------------------------------------------------------------------
// Kernel 1: per-block expm via Taylor series (||A|| ~ 0.23 -> terms to A^7/7!
// leave ~1e-7 residual). One workgroup per block, all matmuls in LDS.
// Output: Bt[k][c][b] = expm(A_k)[b][c] in bf16 (transposed for MFMA B-frags).
// ---------------------------------------------------------------------------
__global__ __launch_bounds__(512) void expm_kernel(
        const float* __restrict__ skew, ushort* __restrict__ Bt) {
    __shared__ float Asm[BLK][P68];
    __shared__ float Tb[2][BLK][P68];
    __shared__ float Rm[BLK][P68];
    const int k   = blockIdx.x;
    const int tid = threadIdx.x;
    const float* P = skew + (size_t)k * (BLK * BLK);

    for (int e = tid; e < BLK * BLK; e += 512) {
        const int i = e >> 6, j = e & 63;
        const float a = P[i * BLK + j] - P[j * BLK + i];   // A = P - P^T
        Asm[i][j]   = a;
        Tb[0][i][j] = a;                                   // T_1 = A
        Rm[i][j]    = a + (i == j ? 1.0f : 0.0f);          // R = I + A
    }
    __syncthreads();

    const int i0 = (tid >> 4) * 2;   // 32 row-groups x 2 rows
    const int j0 = (tid & 15) * 4;   // 16 col-groups x 4 cols

    for (int n = 2; n <= 7; ++n) {   // T_n = T_{n-1} * A / n ; R += T_n
        const float invn = 1.0f / (float)n;
        const float (*Tc)[P68] = Tb[n & 1];        // T_1 lives in Tb[0] (n=2 reads idx 0)
        float       (*Tn)[P68] = Tb[1 - (n & 1)];
        f32x4 acc0 = {0.f, 0.f, 0.f, 0.f}, acc1 = {0.f, 0.f, 0.f, 0.f};
        for (int b = 0; b < BLK; ++b) {
            const f32x4 av = *(const f32x4*)&Asm[b][j0];
            acc0 += Tc[i0][b]     * av;
            acc1 += Tc[i0 + 1][b] * av;
        }
        acc0 *= invn; acc1 *= invn;
        *(f32x4*)&Tn[i0][j0]     = acc0;
        *(f32x4*)&Tn[i0 + 1][j0] = acc1;
        f32x4 r0 = *(const f32x4*)&Rm[i0][j0];     r0 += acc0; *(f32x4*)&Rm[i0][j0]     = r0;
        f32x4 r1 = *(const f32x4*)&Rm[i0 + 1][j0]; r1 += acc1; *(f32x4*)&Rm[i0 + 1][j0] = r1;
        __syncthreads();
    }

    for (int e = tid; e < BLK * BLK; e += 512) {
        const int c = e >> 6, b = e & 63;
        Bt[((size_t)k * BLK + c) * BLK + b] = (ushort)f2bf(Rm[b][c]);
    }
}

// ---------------------------------------------------------------------------
// Kernel 2: main. One workgroup = 16 rows x full 1024 cols.
//   - 8 waves: wave = (kw, n0) handles block kp*2+kw, col-tile n0 (16 cols).
//   - A-frags: x loaded f32 from global (each 64B line consumed by one lane),
//     converted bf16 in-register. B-frags: contiguous 16B loads from Bt.
//   - 2x mfma_f32_16x16x32_bf16 per 16x16 C tile (K=64), f32 accum.
//   - C/D layout (m89-verified): col = lane&15, row = (lane>>4)*4 + reg.
//   - y assembled f32 in LDS; no barriers in k-loop (waves own disjoint cols);
//     one barrier, then permuted gather from LDS + dense float4 stores.
// ---------------------------------------------------------------------------
__global__ __launch_bounds__(MAIN_THREADS, 4) void gsl_main_kernel(
        const float* __restrict__ x, const ushort* __restrict__ Bt,
        const int* __restrict__ perm, float* __restrict__ out) {
    __shared__ float ylds[RT][DIM + 4];   // pad 4 floats: spreads write banks
    __shared__ int   plds[DIM];

    const int tid = threadIdx.x;
    const int r0  = blockIdx.x * RT;

    for (int i = tid; i < DIM; i += MAIN_THREADS) plds[i] = perm[i];

    const int wave = tid >> 6;          // 0..7
    const int lane = tid & 63;
    const int g    = lane >> 4;         // k-group 0..3
    const int m16  = lane & 15;         // A-row / B-col / D-col within tile
    const int kw   = wave >> 2;         // block within pair
    const int n0   = (wave & 3) << 4;   // col-tile base within block

    for (int kp = 0; kp < NB / 2; ++kp) {
        const int k = kp * 2 + kw;
        const float* xp = x + (size_t)(r0 + m16) * DIM + k * BLK + g * 8;
        const f32x4 xa0 = *(const f32x4*)(xp + 0);    // kk = g*8 + 0..3
        const f32x4 xa1 = *(const f32x4*)(xp + 4);    // kk = g*8 + 4..7
        const f32x4 xb0 = *(const f32x4*)(xp + 32);   // kk = 32 + g*8 + 0..3
        const f32x4 xb1 = *(const f32x4*)(xp + 36);

        bf16x8 alo, ahi;
        alo[0] = f2bf(xa0[0]); alo[1] = f2bf(xa0[1]); alo[2] = f2bf(xa0[2]); alo[3] = f2bf(xa0[3]);
        alo[4] = f2bf(xa1[0]); alo[5] = f2bf(xa1[1]); alo[6] = f2bf(xa1[2]); alo[7] = f2bf(xa1[3]);
        ahi[0] = f2bf(xb0[0]); ahi[1] = f2bf(xb0[1]); ahi[2] = f2bf(xb0[2]); ahi[3] = f2bf(xb0[3]);
        ahi[4] = f2bf(xb1[0]); ahi[5] = f2bf(xb1[1]); ahi[6] = f2bf(xb1[2]); ahi[7] = f2bf(xb1[3]);

        // B-frag: lane holds B[kk][n] = Bt[k][n][kk], n = n0+m16, kk = g*8+j
        const ushort* bp = Bt + ((size_t)(k * BLK) + n0 + m16) * BLK + g * 8;
        const bf16x8 blo = *(const bf16x8*)(bp);
        const bf16x8 bhi = *(const bf16x8*)(bp + 32);

        f32x4 acc = {0.f, 0.f, 0.f, 0.f};
        acc = __builtin_amdgcn_mfma_f32_16x16x32_bf16(alo, blo, acc, 0, 0, 0);
        acc = __builtin_amdgcn_mfma_f32_16x16x32_bf16(ahi, bhi, acc, 0, 0, 0);

        const int col = k * BLK + n0 + m16;
#pragma unroll
        for (int i = 0; i < 4; ++i)
            ylds[g * 4 + i][col] = acc[i];
    }

    __syncthreads();

    // Permuted epilogue: out[r][j] = y[r][perm[j]], dense float4 stores.
    const int r = tid >> 5;          // 16 rows, 32 threads per row
    const int q = tid & 31;
    const float* yrow = &ylds[r][0];
    float* orow = out + (size_t)(r0 + r) * DIM;
#pragma unroll
    for (int i = 0; i < 8; ++i) {
        const int c4 = (q + 32 * i) << 2;
        f32x4 v;
        v[0] = yrow[plds[c4 + 0]];
        v[1] = yrow[plds[c4 + 1]];
        v[2] = yrow[plds[c4 + 2]];
        v[3] = yrow[plds[c4 + 3]];
        *(f32x4*)(orow + c4) = v;
    }
}

// ---------------------------------------------------------------------------
extern "C" void kernel_launch(void* const* d_in, const int* in_sizes, int n_in,
                              void* d_out, int out_size, void* d_ws, size_t ws_size,
                              hipStream_t stream) {
    const float* x    = (const float*)d_in[0];   // [65536, 1024] f32
    const float* skew = (const float*)d_in[1];   // [16, 64, 64] f32
    const int*   perm = (const int*)d_in[2];     // [1024] int32 or int64 (detected)
    float* out = (float*)d_out;

    // ws layout: [0,128KB) Bt bf16 [16][64][64] transposed; [128KB,+4KB) perm i32
    ushort* Bt     = (ushort*)d_ws;
    int*    perm_i = (int*)((char*)d_ws + (size_t)NB * BLK * BLK * sizeof(ushort));

    decode_perm_kernel<<<1, 256, 0, stream>>>(perm, perm_i);
    expm_kernel<<<NB, 512, 0, stream>>>(skew, Bt);
    gsl_main_kernel<<<65536 / RT, MAIN_THREADS, 0, stream>>>(x, Bt, perm_i, out);
}

// Round 4
// 141.973 us; speedup vs baseline: 1.6644x; 1.6644x over previous
//
#include <hip/hip_runtime.h>

#define DIM           1024
#define BLK           64
#define NB            16      // DIM/BLK
#define RT            16      // rows per tile
#define MAIN_THREADS  512
#define NWG           512     // persistent: 2 per CU
#define NTILES        4096    // 65536 / RT
#define P68           68      // padded LDS row for expm
#define BFRAG_STRIDE  512     // ushorts per (k,n0,h) B-frag block: 64 lanes x 8

typedef float  f32x4  __attribute__((ext_vector_type(4)));
typedef short  bf16x8 __attribute__((ext_vector_type(8)));

// f32 -> bf16 bits, round-to-nearest-even
static __device__ __forceinline__ short f2bf(float f) {
    union { float f; unsigned u; } v; v.f = f;
    unsigned r = v.u + 0x7fffu + ((v.u >> 16) & 1u);
    return (short)(r >> 16);
}

// async global->LDS, 16B per lane (dest is wave-uniform base + lane*16)
static __device__ __forceinline__ void gload16(const float* g, void* l) {
    __builtin_amdgcn_global_load_lds(
        (const __attribute__((address_space(1))) unsigned int*)g,
        (__attribute__((address_space(3))) unsigned int*)l, 16, 0, 0);
}

// ---------------------------------------------------------------------------
// Kernel 0: normalize perm to int32 in ws (int64 vs int32 runtime detect:
// int64 read as int32 pairs gives ~512 zero high-words; int32 perm has one 0).
// ---------------------------------------------------------------------------
__global__ void decode_perm_kernel(const int* __restrict__ praw,
                                   int* __restrict__ pout) {
    __shared__ int zc;
    if (threadIdx.x == 0) zc = 0;
    __syncthreads();
    int local = 0;
    for (int i = threadIdx.x; i < DIM; i += blockDim.x)
        if (praw[i] == 0) local++;
    if (local) atomicAdd(&zc, local);
    __syncthreads();
    const bool is64 = (zc > 100);
    const long long* p64 = (const long long*)praw;
    for (int i = threadIdx.x; i < DIM; i += blockDim.x)
        pout[i] = is64 ? (int)p64[i] : praw[i];
}

// ---------------------------------------------------------------------------
// Kernel 1: per-block expm via Taylor to A^7/7!. Output layout is MFMA-B-frag
// lane-linear: Btl[((k*4+n)*2+h)*512 + g*128 + m*8 + j]
//            = B_k[h*32+g*8+j][n*16+m], bf16. (512 ushorts per frag block.)
// ---------------------------------------------------------------------------
__global__ __launch_bounds__(512) void expm_kernel(
        const float* __restrict__ skew, ushort* __restrict__ Btl) {
    __shared__ float Asm[BLK][P68];
    __shared__ float Tb[2][BLK][P68];
    __shared__ float Rm[BLK][P68];
    const int k   = blockIdx.x;
    const int tid = threadIdx.x;
    const float* P = skew + (size_t)k * (BLK * BLK);

    for (int e = tid; e < BLK * BLK; e += 512) {
        const int i = e >> 6, j = e & 63;
        const float a = P[i * BLK + j] - P[j * BLK + i];   // A = P - P^T
        Asm[i][j]   = a;
        Tb[0][i][j] = a;                                   // T_1 = A
        Rm[i][j]    = a + (i == j ? 1.0f : 0.0f);          // R = I + A
    }
    __syncthreads();

    const int i0 = (tid >> 4) * 2;
    const int j0 = (tid & 15) * 4;

    for (int n = 2; n <= 7; ++n) {   // T_n = T_{n-1} * A / n ; R += T_n
        const float invn = 1.0f / (float)n;
        const float (*Tc)[P68] = Tb[n & 1];
        float       (*Tn)[P68] = Tb[1 - (n & 1)];
        f32x4 acc0 = {0.f, 0.f, 0.f, 0.f}, acc1 = {0.f, 0.f, 0.f, 0.f};
        for (int b = 0; b < BLK; ++b) {
            const f32x4 av = *(const f32x4*)&Asm[b][j0];
            acc0 += Tc[i0][b]     * av;
            acc1 += Tc[i0 + 1][b] * av;
        }
        acc0 *= invn; acc1 *= invn;
        *(f32x4*)&Tn[i0][j0]     = acc0;
        *(f32x4*)&Tn[i0 + 1][j0] = acc1;
        f32x4 r0 = *(const f32x4*)&Rm[i0][j0];     r0 += acc0; *(f32x4*)&Rm[i0][j0]     = r0;
        f32x4 r1 = *(const f32x4*)&Rm[i0 + 1][j0]; r1 += acc1; *(f32x4*)&Rm[i0 + 1][j0] = r1;
        __syncthreads();
    }

    for (int e = tid; e < BLK * BLK; e += 512) {
        const int b = e >> 6, c = e & 63;        // value B[b][c]
        const int n = c >> 4, m = c & 15;
        const int h = b >> 5, g = (b >> 3) & 3, j = b & 7;
        const size_t idx = (size_t)((k * 4 + n) * 2 + h) * BFRAG_STRIDE
                         + g * 128 + m * 8 + j;
        Btl[idx] = (ushort)f2bf(Rm[b][c]);
    }
}

// ---------------------------------------------------------------------------
// Kernel 2: persistent main. 512 WGs x 8 tiles; per tile:
//   stage x[16][1024] f32 -> LDS via global_load_lds (fully coalesced, XOR
//   slot-swizzle pre-applied on the global source), barrier, each wave
//   computes its 2 blocks (A-frags: swizzled ds_read_b128; B-frags resident
//   in VGPRs), overwrites x with y in place, barrier, permuted gather +
//   dense float4 stores.
// LDS layout: chunk k2 = col/128; phys byte addr of (k2,row,slot,dword) =
//   k2*8192 + row*512 + ((slot ^ (row&7))<<4) + dword*4.
// ---------------------------------------------------------------------------
__global__ __launch_bounds__(MAIN_THREADS, 4) void gsl_main_kernel(
        const float* __restrict__ x, const ushort* __restrict__ Btl,
        const int* __restrict__ perm, float* __restrict__ out) {
    __shared__ float xy[16384];        // 64 KB x/y tile (shared buffer)
    __shared__ int   plds[DIM];

    const int tid  = threadIdx.x;
    const int lane = tid & 63;
    const int w    = tid >> 6;         // wave 0..7
    const int g    = lane >> 4;        // k-group 0..3
    const int m16  = lane & 15;

    for (int i = tid; i < DIM; i += MAIN_THREADS) plds[i] = perm[i];

    // Persistent B-frags: wave w owns blocks w and w+8. 16 x bf16x8 = 64 VGPR.
    bf16x8 bf[2][4][2];                // [blk][n0][h]
#pragma unroll
    for (int b = 0; b < 2; ++b) {
        const int k = w + 8 * b;
#pragma unroll
        for (int n = 0; n < 4; ++n)
#pragma unroll
            for (int h = 0; h < 2; ++h)
                bf[b][n][h] = *(const bf16x8*)(Btl +
                    (size_t)((k * 4 + n) * 2 + h) * BFRAG_STRIDE + lane * 8);
    }

    char* const xyb = (char*)xy;

    // staging address pattern (constant per thread): thread t writes LDS
    // linear t*16 + s*8192; logical (row=t>>5, slot=(t&31)^(row&7)).
    const int srow  = tid >> 5;
    const int sslot = (tid & 31) ^ (srow & 7);
    char* const ldst0 = xyb + tid * 16;

    for (int it = 0; it < NTILES / NWG; ++it) {
        const int    tile = blockIdx.x + it * NWG;
        const size_t r0   = (size_t)tile * RT;

        if (it) __syncthreads();                     // prev epilogue done
        const float* gsrc = x + (r0 + srow) * DIM + sslot * 4;
#pragma unroll
        for (int s = 0; s < 8; ++s)                  // 8 chunks x 8 KB
            gload16(gsrc + s * 128, ldst0 + s * 8192);
        __syncthreads();                             // stage complete (vmcnt0)

        // ---- compute: wave w -> blocks w, w+8 ----
#pragma unroll
        for (int b = 0; b < 2; ++b) {
            const int k  = w + 8 * b;
            const int k2 = k >> 1;
            const int sb = (k & 1) * 16;             // slot base in chunk
            const char* rowp = xyb + k2 * 8192 + m16 * 512;
            const int   xs   = m16 & 7;
            const f32x4 a0 = *(const f32x4*)(rowp + (((sb + 2 * g    ) ^ xs) << 4));
            const f32x4 a1 = *(const f32x4*)(rowp + (((sb + 2 * g + 1) ^ xs) << 4));
            const f32x4 a2 = *(const f32x4*)(rowp + (((sb + 8 + 2 * g    ) ^ xs) << 4));
            const f32x4 a3 = *(const f32x4*)(rowp + (((sb + 8 + 2 * g + 1) ^ xs) << 4));
            bf16x8 alo, ahi;
            alo[0] = f2bf(a0[0]); alo[1] = f2bf(a0[1]); alo[2] = f2bf(a0[2]); alo[3] = f2bf(a0[3]);
            alo[4] = f2bf(a1[0]); alo[5] = f2bf(a1[1]); alo[6] = f2bf(a1[2]); alo[7] = f2bf(a1[3]);
            ahi[0] = f2bf(a2[0]); ahi[1] = f2bf(a2[1]); ahi[2] = f2bf(a2[2]); ahi[3] = f2bf(a2[3]);
            ahi[4] = f2bf(a3[0]); ahi[5] = f2bf(a3[1]); ahi[6] = f2bf(a3[2]); ahi[7] = f2bf(a3[3]);

            f32x4 acc[4];
#pragma unroll
            for (int n = 0; n < 4; ++n) acc[n] = (f32x4){0.f, 0.f, 0.f, 0.f};
#pragma unroll
            for (int n = 0; n < 4; ++n)
                acc[n] = __builtin_amdgcn_mfma_f32_16x16x32_bf16(alo, bf[b][n][0], acc[n], 0, 0, 0);
#pragma unroll
            for (int n = 0; n < 4; ++n)
                acc[n] = __builtin_amdgcn_mfma_f32_16x16x32_bf16(ahi, bf[b][n][1], acc[n], 0, 0, 0);

            // y overwrites x in place (wave-disjoint column ranges)
#pragma unroll
            for (int n = 0; n < 4; ++n) {
                const int c    = sb * 4 + n * 16 + m16;   // col in 128-chunk
                const int slot = c >> 2;
                const int d    = (c & 3) * 4;
#pragma unroll
                for (int i = 0; i < 4; ++i) {
                    const int row = g * 4 + i;
                    *(float*)(xyb + k2 * 8192 + row * 512 +
                              (((slot ^ (row & 7)) << 4)) + d) = acc[n][i];
                }
            }
        }
        __syncthreads();                             // y tile complete

        // ---- permuted epilogue: out[r][j] = y[r][perm[j]] ----
        const int   r   = tid >> 5;
        const int   q   = tid & 31;
        const int   rx  = r & 7;
        const char* rb  = xyb + r * 512;
        float*      orow = out + (r0 + r) * DIM;
#pragma unroll
        for (int i2 = 0; i2 < 8; ++i2) {
            const int c4 = (q + 32 * i2) << 2;
            f32x4 v;
#pragma unroll
            for (int u = 0; u < 4; ++u) {
                const int p = plds[c4 + u];
                v[u] = *(const float*)(rb + (p >> 7) * 8192 +
                                       ((((p >> 2) & 31) ^ rx) << 4) + (p & 3) * 4);
            }
            *(f32x4*)(orow + c4) = v;
        }
    }
}

// ---------------------------------------------------------------------------
extern "C" void kernel_launch(void* const* d_in, const int* in_sizes, int n_in,
                              void* d_out, int out_size, void* d_ws, size_t ws_size,
                              hipStream_t stream) {
    const float* x    = (const float*)d_in[0];   // [65536, 1024] f32
    const float* skew = (const float*)d_in[1];   // [16, 64, 64] f32
    const int*   perm = (const int*)d_in[2];     // [1024] i32/i64 (detected)
    float* out = (float*)d_out;

    // ws: [0,128KB) Btl bf16 lane-linear; [128KB,+4KB) perm i32
    ushort* Btl    = (ushort*)d_ws;
    int*    perm_i = (int*)((char*)d_ws + (size_t)NB * BLK * BLK * sizeof(ushort));

    decode_perm_kernel<<<1, 256, 0, stream>>>(perm, perm_i);
    expm_kernel<<<NB, 512, 0, stream>>>(skew, Btl);
    gsl_main_kernel<<<NWG, MAIN_THREADS, 0, stream>>>(x, Btl, perm_i, out);
}

// Round 5
// 134.903 us; speedup vs baseline: 1.7516x; 1.0524x over previous
//
#include <hip/hip_runtime.h>

#define DIM           1024
#define BLK           64
#define NB            16      // DIM/BLK
#define RT            16      // rows per tile
#define MAIN_THREADS  512
#define NWG           256     // persistent: 1 per CU (132 KB LDS)
#define NT            16      // tiles per WG (4096 / 256)
#define P68           68      // padded LDS row for expm
#define BFRAG_STRIDE  512     // ushorts per (k,n0,h) B-frag block: 64 lanes x 8

typedef float  f32x4  __attribute__((ext_vector_type(4)));
typedef short  bf16x8 __attribute__((ext_vector_type(8)));

// f32 -> bf16 bits, round-to-nearest-even
static __device__ __forceinline__ short f2bf(float f) {
    union { float f; unsigned u; } v; v.f = f;
    unsigned r = v.u + 0x7fffu + ((v.u >> 16) & 1u);
    return (short)(r >> 16);
}

// async global->LDS, 16B per lane (dest is wave-uniform base + lane*16)
static __device__ __forceinline__ void gload16(const float* g, void* l) {
    __builtin_amdgcn_global_load_lds(
        (const __attribute__((address_space(1))) unsigned int*)g,
        (__attribute__((address_space(3))) unsigned int*)l, 16, 0, 0);
}

#define WAITV8()  asm volatile("s_waitcnt vmcnt(8)"  ::: "memory")
#define WAITV16() asm volatile("s_waitcnt vmcnt(16)" ::: "memory")
#define WAITL()   asm volatile("s_waitcnt lgkmcnt(0)" ::: "memory")
#define SBAR()    __builtin_amdgcn_s_barrier()
#define SCHED0()  __builtin_amdgcn_sched_barrier(0)

// ---------------------------------------------------------------------------
// Kernel 1 (fused): blocks 0..15 = per-block expm (Taylor to A^7/7!);
// block 16 = perm int64/int32 decode into ws.
// Btl[((k*4+n)*2+h)*512 + g*128 + m*8 + j] = B_k[h*32+g*8+j][n*16+m], bf16.
// ---------------------------------------------------------------------------
__global__ __launch_bounds__(512) void expm_kernel(
        const float* __restrict__ skew, ushort* __restrict__ Btl,
        const int* __restrict__ praw, int* __restrict__ pout) {
    __shared__ float Asm[BLK][P68];
    __shared__ float Tb[2][BLK][P68];
    __shared__ float Rm[BLK][P68];
    const int tid = threadIdx.x;

    if (blockIdx.x == NB) {                 // ---- perm decode ----
        __shared__ int zc;
        if (tid == 0) zc = 0;
        __syncthreads();
        int local = 0;
        for (int i = tid; i < DIM; i += 512)
            if (praw[i] == 0) local++;
        if (local) atomicAdd(&zc, local);
        __syncthreads();
        const bool is64 = (zc > 100);       // i64 read as i32: ~512 zero hi-words
        const long long* p64 = (const long long*)praw;
        for (int i = tid; i < DIM; i += 512)
            pout[i] = is64 ? (int)p64[i] : praw[i];
        return;
    }

    const int k = blockIdx.x;
    const float* P = skew + (size_t)k * (BLK * BLK);

    for (int e = tid; e < BLK * BLK; e += 512) {
        const int i = e >> 6, j = e & 63;
        const float a = P[i * BLK + j] - P[j * BLK + i];   // A = P - P^T
        Asm[i][j]   = a;
        Tb[0][i][j] = a;                                   // T_1 = A
        Rm[i][j]    = a + (i == j ? 1.0f : 0.0f);          // R = I + A
    }
    __syncthreads();

    const int i0 = (tid >> 4) * 2;
    const int j0 = (tid & 15) * 4;

    for (int n = 2; n <= 7; ++n) {   // T_n = T_{n-1} * A / n ; R += T_n
        const float invn = 1.0f / (float)n;
        const float (*Tc)[P68] = Tb[n & 1];
        float       (*Tn)[P68] = Tb[1 - (n & 1)];
        f32x4 acc0 = {0.f, 0.f, 0.f, 0.f}, acc1 = {0.f, 0.f, 0.f, 0.f};
        for (int b = 0; b < BLK; ++b) {
            const f32x4 av = *(const f32x4*)&Asm[b][j0];
            acc0 += Tc[i0][b]     * av;
            acc1 += Tc[i0 + 1][b] * av;
        }
        acc0 *= invn; acc1 *= invn;
        *(f32x4*)&Tn[i0][j0]     = acc0;
        *(f32x4*)&Tn[i0 + 1][j0] = acc1;
        f32x4 r0 = *(const f32x4*)&Rm[i0][j0];     r0 += acc0; *(f32x4*)&Rm[i0][j0]     = r0;
        f32x4 r1 = *(const f32x4*)&Rm[i0 + 1][j0]; r1 += acc1; *(f32x4*)&Rm[i0 + 1][j0] = r1;
        __syncthreads();
    }

    for (int e = tid; e < BLK * BLK; e += 512) {
        const int b = e >> 6, c = e & 63;        // value B[b][c]
        const int n = c >> 4, m = c & 15;
        const int h = b >> 5, g = (b >> 3) & 3, j = b & 7;
        const size_t idx = (size_t)((k * 4 + n) * 2 + h) * BFRAG_STRIDE
                         + g * 128 + m * 8 + j;
        Btl[idx] = (ushort)f2bf(Rm[b][c]);
    }
}

// ---------------------------------------------------------------------------
// Kernel 2: persistent main, double-buffered counted-vmcnt pipeline.
// 256 WGs x 16 tiles. Per tile: epilogue(prev) -> stage(next, same buffer)
// -> vmcnt(counted) + raw barrier -> compute (y overwrites x in place)
// -> lgkmcnt(0) + raw barrier.
// LDS tile layout (per buffer): chunk k2=col/128; byte(k2,row,slot,dw) =
//   k2*8192 + row*512 + ((slot^(row&7))<<4) + dw*4.  Stage rows per wave
//   {2w,2w+1} == epilogue rows per wave -> stage-after-epilogue is wave-local
//   program order; cross-wave y-writes fenced by lgkmcnt(0)+barrier.
// vmcnt ledger (in-order retire): steady outstanding at WAITV =
//   [stores(it-2) 8, stage(it) 8, stores(it-1) 8, stage(it+1) 8] -> 16;
//   first/last iterations -> 8.
// ---------------------------------------------------------------------------
__global__ __launch_bounds__(MAIN_THREADS, 2) void gsl_main_kernel(
        const float* __restrict__ x, const ushort* __restrict__ Btl,
        const int* __restrict__ perm, float* __restrict__ out) {
    __shared__ float xy0[16384];       // 64 KB buffer A
    __shared__ float xy1[16384];       // 64 KB buffer B
    __shared__ int   plds[DIM];

    const int tid  = threadIdx.x;
    const int lane = tid & 63;
    const int w    = tid >> 6;         // wave 0..7
    const int g    = lane >> 4;        // k-group 0..3
    const int m16  = lane & 15;

    for (int i = tid; i < DIM; i += MAIN_THREADS) plds[i] = perm[i];

    // Persistent B-frags: wave w owns blocks w and w+8 (64 VGPR).
    bf16x8 bf[2][4][2];                // [blk][n0][h]
#pragma unroll
    for (int b = 0; b < 2; ++b) {
        const int k = w + 8 * b;
#pragma unroll
        for (int n = 0; n < 4; ++n)
#pragma unroll
            for (int h = 0; h < 2; ++h)
                bf[b][n][h] = *(const bf16x8*)(Btl +
                    (size_t)((k * 4 + n) * 2 + h) * BFRAG_STRIDE + lane * 8);
    }

    const int srow  = tid >> 5;                    // staged/epilogue row
    const int sslot = (tid & 31) ^ (srow & 7);     // inverse-swizzled source slot
    const int tile0 = blockIdx.x * NT;

    auto stage = [&](int it, float* buf) {
        const size_t r0   = (size_t)(tile0 + it) * RT;
        const float* gsrc = x + (r0 + srow) * DIM + sslot * 4;
        char*        ldst = (char*)buf + tid * 16;
#pragma unroll
        for (int s = 0; s < 8; ++s)                // 8 chunks x 8 KB
            gload16(gsrc + s * 128, ldst + s * 8192);
    };

    auto compute = [&](float* buf) {
        char* const xyb = (char*)buf;
#pragma unroll
        for (int b = 0; b < 2; ++b) {
            const int k  = w + 8 * b;
            const int k2 = k >> 1;
            const int sb = (k & 1) * 16;
            const char* rowp = xyb + k2 * 8192 + m16 * 512;
            const int   xs   = m16 & 7;
            const f32x4 a0 = *(const f32x4*)(rowp + (((sb + 2 * g    ) ^ xs) << 4));
            const f32x4 a1 = *(const f32x4*)(rowp + (((sb + 2 * g + 1) ^ xs) << 4));
            const f32x4 a2 = *(const f32x4*)(rowp + (((sb + 8 + 2 * g    ) ^ xs) << 4));
            const f32x4 a3 = *(const f32x4*)(rowp + (((sb + 8 + 2 * g + 1) ^ xs) << 4));
            bf16x8 alo, ahi;
            alo[0] = f2bf(a0[0]); alo[1] = f2bf(a0[1]); alo[2] = f2bf(a0[2]); alo[3] = f2bf(a0[3]);
            alo[4] = f2bf(a1[0]); alo[5] = f2bf(a1[1]); alo[6] = f2bf(a1[2]); alo[7] = f2bf(a1[3]);
            ahi[0] = f2bf(a2[0]); ahi[1] = f2bf(a2[1]); ahi[2] = f2bf(a2[2]); ahi[3] = f2bf(a2[3]);
            ahi[4] = f2bf(a3[0]); ahi[5] = f2bf(a3[1]); ahi[6] = f2bf(a3[2]); ahi[7] = f2bf(a3[3]);

            f32x4 acc[4];
#pragma unroll
            for (int n = 0; n < 4; ++n) acc[n] = (f32x4){0.f, 0.f, 0.f, 0.f};
#pragma unroll
            for (int n = 0; n < 4; ++n)
                acc[n] = __builtin_amdgcn_mfma_f32_16x16x32_bf16(alo, bf[b][n][0], acc[n], 0, 0, 0);
#pragma unroll
            for (int n = 0; n < 4; ++n)
                acc[n] = __builtin_amdgcn_mfma_f32_16x16x32_bf16(ahi, bf[b][n][1], acc[n], 0, 0, 0);

            // y overwrites x in place (wave-disjoint column ranges)
#pragma unroll
            for (int n = 0; n < 4; ++n) {
                const int c    = sb * 4 + n * 16 + m16;
                const int slot = c >> 2;
                const int d    = (c & 3) * 4;
#pragma unroll
                for (int i = 0; i < 4; ++i) {
                    const int row = g * 4 + i;
                    *(float*)(xyb + k2 * 8192 + row * 512 +
                              (((slot ^ (row & 7)) << 4)) + d) = acc[n][i];
                }
            }
        }
    };

    auto epilogue = [&](int it, const float* buf) {
        const size_t r0  = (size_t)(tile0 + it) * RT;
        const int    q   = tid & 31;
        const int    rx  = srow & 7;
        const char*  rb  = (const char*)buf + srow * 512;
        float*       orow = out + (r0 + srow) * DIM;
#pragma unroll
        for (int i2 = 0; i2 < 8; ++i2) {
            const int c4 = (q + 32 * i2) << 2;
            f32x4 v;
#pragma unroll
            for (int u = 0; u < 4; ++u) {
                const int p = plds[c4 + u];
                v[u] = *(const float*)(rb + (p >> 7) * 8192 +
                                       ((((p >> 2) & 31) ^ rx) << 4) + (p & 3) * 4);
            }
            *(f32x4*)(orow + c4) = v;
        }
    };

    // ---- pipeline ----
    stage(0, xy0);

    // it = 0
    stage(1, xy1);
    WAITV8(); SBAR();
    compute(xy0);
    WAITL(); SBAR();

    // middle iterations
    for (int it = 1; it < NT - 1; ++it) {
        float* Xc = (it & 1) ? xy1 : xy0;
        float* Xn = (it & 1) ? xy0 : xy1;
        epilogue(it - 1, Xn);          // tile it-1 lived in the other buffer
        WAITL(); SCHED0();             // epilogue LDS reads done before overwrite
        stage(it + 1, Xn);
        WAITV16(); SBAR();             // stage(it) landed; prefetch stays in flight
        compute(Xc);
        WAITL(); SBAR();
    }

    // it = NT-1 (odd -> buffer xy1)
    epilogue(NT - 2, xy0);
    WAITV8(); SBAR();
    compute(xy1);
    WAITL(); SBAR();
    epilogue(NT - 1, xy1);
}

// ---------------------------------------------------------------------------
extern "C" void kernel_launch(void* const* d_in, const int* in_sizes, int n_in,
                              void* d_out, int out_size, void* d_ws, size_t ws_size,
                              hipStream_t stream) {
    const float* x    = (const float*)d_in[0];   // [65536, 1024] f32
    const float* skew = (const float*)d_in[1];   // [16, 64, 64] f32
    const int*   perm = (const int*)d_in[2];     // [1024] i32/i64 (detected)
    float* out = (float*)d_out;

    // ws: [0,128KB) Btl bf16 lane-linear; [128KB,+4KB) perm i32
    ushort* Btl    = (ushort*)d_ws;
    int*    perm_i = (int*)((char*)d_ws + (size_t)NB * BLK * BLK * sizeof(ushort));

    expm_kernel<<<NB + 1, 512, 0, stream>>>(skew, Btl, perm, perm_i);
    gsl_main_kernel<<<NWG, MAIN_THREADS, 0, stream>>>(x, Btl, perm_i, out);
}

// Round 6
// 131.030 us; speedup vs baseline: 1.8034x; 1.0296x over previous
//
#include <hip/hip_runtime.h>

#define DIM           1024
#define BLK           64
#define NB            16      // DIM/BLK
#define RT            16      // rows per tile
#define MAIN_THREADS  1024    // 16 waves; wave w owns block w
#define NWG           256     // persistent: 1 per CU
#define NT            16      // tiles per WG (4096 / 256)
#define P68           68      // padded LDS row for expm
#define BFRAG_STRIDE  512     // ushorts per (k,n0,h) B-frag block: 64 lanes x 8

typedef float  f32x4  __attribute__((ext_vector_type(4)));
typedef short  bf16x8 __attribute__((ext_vector_type(8)));

// f32 -> bf16 bits, round-to-nearest-even
static __device__ __forceinline__ short f2bf(float f) {
    union { float f; unsigned u; } v; v.f = f;
    unsigned r = v.u + 0x7fffu + ((v.u >> 16) & 1u);
    return (short)(r >> 16);
}

#define WAITL()   asm volatile("s_waitcnt lgkmcnt(0)" ::: "memory")
#define SBAR()    __builtin_amdgcn_s_barrier()

// ---------------------------------------------------------------------------
// Kernel 1 (fused): blocks 0..15 = per-block expm (Taylor to A^7/7!);
// block 16 = perm decode -> INVERSE permutation pinv (pinv[perm[j]] = j).
// Btl[((k*4+n)*2+h)*512 + g*128 + m*8 + j] = B_k[h*32+g*8+j][n*16+m], bf16.
// ---------------------------------------------------------------------------
__global__ __launch_bounds__(512) void expm_kernel(
        const float* __restrict__ skew, ushort* __restrict__ Btl,
        const int* __restrict__ praw, int* __restrict__ pinv) {
    __shared__ float Asm[BLK][P68];
    __shared__ float Tb[2][BLK][P68];
    __shared__ float Rm[BLK][P68];
    const int tid = threadIdx.x;

    if (blockIdx.x == NB) {                 // ---- perm decode -> inverse ----
        __shared__ int zc;
        if (tid == 0) zc = 0;
        __syncthreads();
        int local = 0;
        for (int i = tid; i < DIM; i += 512)
            if (praw[i] == 0) local++;
        if (local) atomicAdd(&zc, local);
        __syncthreads();
        const bool is64 = (zc > 100);       // i64 read as i32: ~512 zero hi-words
        const long long* p64 = (const long long*)praw;
        for (int i = tid; i < DIM; i += 512) {
            const int v = is64 ? (int)p64[i] : praw[i];
            pinv[v] = i;
        }
        return;
    }

    const int k = blockIdx.x;
    const float* P = skew + (size_t)k * (BLK * BLK);

    for (int e = tid; e < BLK * BLK; e += 512) {
        const int i = e >> 6, j = e & 63;
        const float a = P[i * BLK + j] - P[j * BLK + i];   // A = P - P^T
        Asm[i][j]   = a;
        Tb[0][i][j] = a;                                   // T_1 = A
        Rm[i][j]    = a + (i == j ? 1.0f : 0.0f);          // R = I + A
    }
    __syncthreads();

    const int i0 = (tid >> 4) * 2;
    const int j0 = (tid & 15) * 4;

    for (int n = 2; n <= 7; ++n) {   // T_n = T_{n-1} * A / n ; R += T_n
        const float invn = 1.0f / (float)n;
        const float (*Tc)[P68] = Tb[n & 1];
        float       (*Tn)[P68] = Tb[1 - (n & 1)];
        f32x4 acc0 = {0.f, 0.f, 0.f, 0.f}, acc1 = {0.f, 0.f, 0.f, 0.f};
        for (int b = 0; b < BLK; ++b) {
            const f32x4 av = *(const f32x4*)&Asm[b][j0];
            acc0 += Tc[i0][b]     * av;
            acc1 += Tc[i0 + 1][b] * av;
        }
        acc0 *= invn; acc1 *= invn;
        *(f32x4*)&Tn[i0][j0]     = acc0;
        *(f32x4*)&Tn[i0 + 1][j0] = acc1;
        f32x4 r0 = *(const f32x4*)&Rm[i0][j0];     r0 += acc0; *(f32x4*)&Rm[i0][j0]     = r0;
        f32x4 r1 = *(const f32x4*)&Rm[i0 + 1][j0]; r1 += acc1; *(f32x4*)&Rm[i0 + 1][j0] = r1;
        __syncthreads();
    }

    for (int e = tid; e < BLK * BLK; e += 512) {
        const int b = e >> 6, c = e & 63;        // value B[b][c]
        const int n = c >> 4, m = c & 15;
        const int h = b >> 5, g = (b >> 3) & 3, j = b & 7;
        const size_t idx = (size_t)((k * 4 + n) * 2 + h) * BFRAG_STRIDE
                         + g * 128 + m * 8 + j;
        Btl[idx] = (ushort)f2bf(Rm[b][c]);
    }
}

// ---------------------------------------------------------------------------
// Kernel 2: persistent main, no x-staging.
// 256 WGs x 16 tiles; 1024 threads = 16 waves; wave w owns block w and
// epilogue row w. Per tile (ONE barrier, zero vmcnt drains):
//   - A-frags: direct global->reg f32x4 loads (prefetched 1 tile ahead;
//     regs freed by bf16 conversion before reuse)
//   - 8x mfma_f32_16x16x32_bf16 -> acc = y[rows g*4+i][cols w*64+n*16+m16]
//   - scatter acc into LDS PRE-PERMUTED: y'[row][j] = y[row][perm[j]] via
//     inv_perm; layout byte(row,j) = (j>>2)*256 + ((row^((j>>2)&15))*16)
//     + (j&3)*4 (XOR slot swizzle -> ~4-way banks both sides)
//   - epilogue(it-1) from other y' buffer: 4x ds_read_b128 + 4x coalesced
//     global_store_dwordx4 per wave; runs concurrently with scatter(it)
// ---------------------------------------------------------------------------
__global__ __launch_bounds__(MAIN_THREADS) void gsl_main_kernel(
        const float* __restrict__ x, const ushort* __restrict__ Btl,
        const int* __restrict__ pinv, float* __restrict__ out) {
    __shared__ float yb[2][16384];     // two 64 KB permuted-y buffers

    const int tid  = threadIdx.x;
    const int lane = tid & 63;
    const int w    = tid >> 6;         // wave 0..15 = block id & epilogue row
    const int g    = lane >> 4;        // 0..3
    const int m16  = lane & 15;

    // B-frags for block w: 8 x bf16x8 = 32 VGPR
    bf16x8 bfr[4][2];
#pragma unroll
    for (int n = 0; n < 4; ++n)
#pragma unroll
        for (int h = 0; h < 2; ++h)
            bfr[n][h] = *(const bf16x8*)(Btl +
                (size_t)((w * 4 + n) * 2 + h) * BFRAG_STRIDE + lane * 8);

    // Scatter-address precompute: for col c = w*64+n*16+m16, j = pinv[c]:
    // byte(row,j) = (j>>2)*256 + ((row ^ ((j>>2)&15))*16) + (j&3)*4
    //             = sbase[n] + ((i ^ sx3[n]) << 4)   with row = 4g+i
    int sbase[4], sx3[4];
#pragma unroll
    for (int n = 0; n < 4; ++n) {
        const int c  = w * 64 + n * 16 + m16;
        const int j  = pinv[c];
        const int g4 = j >> 2;
        sbase[n] = g4 * 256 + (((4 * g) ^ (g4 & 12)) << 4) + (j & 3) * 4;
        sx3[n]   = g4 & 3;
    }

    const int tile0 = blockIdx.x * NT;
    const float* xw = x + w * 64 + g * 8;   // + row*1024 per tile

    // A-reg pipeline (one tile ahead; 16 VGPR, freed by conversion)
    f32x4 a0, a1, a2, a3;
    {
        const float* xp = xw + (size_t)(tile0 * RT + m16) * DIM;
        a0 = *(const f32x4*)(xp);      a1 = *(const f32x4*)(xp + 4);
        a2 = *(const f32x4*)(xp + 32); a3 = *(const f32x4*)(xp + 36);
    }

    for (int it = 0; it < NT; ++it) {
        float*       yc = yb[it & 1];
        const float* yp = yb[(it & 1) ^ 1];

        // convert A(it) -> bf16 (frees a0..a3 for the prefetch)
        bf16x8 alo, ahi;
        alo[0] = f2bf(a0[0]); alo[1] = f2bf(a0[1]); alo[2] = f2bf(a0[2]); alo[3] = f2bf(a0[3]);
        alo[4] = f2bf(a1[0]); alo[5] = f2bf(a1[1]); alo[6] = f2bf(a1[2]); alo[7] = f2bf(a1[3]);
        ahi[0] = f2bf(a2[0]); ahi[1] = f2bf(a2[1]); ahi[2] = f2bf(a2[2]); ahi[3] = f2bf(a2[3]);
        ahi[4] = f2bf(a3[0]); ahi[5] = f2bf(a3[1]); ahi[6] = f2bf(a3[2]); ahi[7] = f2bf(a3[3]);

        if (it + 1 < NT) {             // prefetch A(it+1)
            const float* xp = xw + (size_t)((tile0 + it + 1) * RT + m16) * DIM;
            a0 = *(const f32x4*)(xp);      a1 = *(const f32x4*)(xp + 4);
            a2 = *(const f32x4*)(xp + 32); a3 = *(const f32x4*)(xp + 36);
        }

        // MFMA: acc[n][i] = y[4g+i][w*64 + n*16 + m16]
        f32x4 acc[4];
#pragma unroll
        for (int n = 0; n < 4; ++n) acc[n] = (f32x4){0.f, 0.f, 0.f, 0.f};
#pragma unroll
        for (int n = 0; n < 4; ++n)
            acc[n] = __builtin_amdgcn_mfma_f32_16x16x32_bf16(alo, bfr[n][0], acc[n], 0, 0, 0);
#pragma unroll
        for (int n = 0; n < 4; ++n)
            acc[n] = __builtin_amdgcn_mfma_f32_16x16x32_bf16(ahi, bfr[n][1], acc[n], 0, 0, 0);

        // scatter into pre-permuted y'(it)
        char* const ycb = (char*)yc;
#pragma unroll
        for (int n = 0; n < 4; ++n)
#pragma unroll
            for (int i = 0; i < 4; ++i)
                *(float*)(ycb + sbase[n] + ((i ^ sx3[n]) << 4)) = acc[n][i];

        // epilogue(it-1) from the other buffer: linear reads, coalesced stores
        if (it) {
            const char* ypb  = (const char*)yp;
            float*      orow = out + (size_t)((tile0 + it - 1) * RT + w) * DIM;
#pragma unroll
            for (int i2 = 0; i2 < 4; ++i2) {
                const int j4   = lane + 64 * i2;
                const int slot = w ^ (j4 & 15);
                const f32x4 v  = *(const f32x4*)(ypb + j4 * 256 + slot * 16);
                *(f32x4*)(orow + j4 * 4) = v;
            }
        }

        WAITL(); SBAR();               // scatter visible; epilogue reads done
    }

    // final epilogue: tile NT-1 from yb[(NT-1)&1]
    {
        const char* ypb  = (const char*)yb[(NT - 1) & 1];
        float*      orow = out + (size_t)((tile0 + NT - 1) * RT + w) * DIM;
#pragma unroll
        for (int i2 = 0; i2 < 4; ++i2) {
            const int j4   = lane + 64 * i2;
            const int slot = w ^ (j4 & 15);
            const f32x4 v  = *(const f32x4*)(ypb + j4 * 256 + slot * 16);
            *(f32x4*)(orow + j4 * 4) = v;
        }
    }
}

// ---------------------------------------------------------------------------
extern "C" void kernel_launch(void* const* d_in, const int* in_sizes, int n_in,
                              void* d_out, int out_size, void* d_ws, size_t ws_size,
                              hipStream_t stream) {
    const float* x    = (const float*)d_in[0];   // [65536, 1024] f32
    const float* skew = (const float*)d_in[1];   // [16, 64, 64] f32
    const int*   perm = (const int*)d_in[2];     // [1024] i32/i64 (detected)
    float* out = (float*)d_out;

    // ws: [0,128KB) Btl bf16 lane-linear; [128KB,+4KB) inverse perm i32
    ushort* Btl  = (ushort*)d_ws;
    int*    pinv = (int*)((char*)d_ws + (size_t)NB * BLK * BLK * sizeof(ushort));

    expm_kernel<<<NB + 1, 512, 0, stream>>>(skew, Btl, perm, pinv);
    gsl_main_kernel<<<NWG, MAIN_THREADS, 0, stream>>>(x, Btl, pinv, out);
}